// Round 10
// baseline (139.390 us; speedup 1.0000x reference)
//
#include <hip/hip_runtime.h>

#define N_NODES 100000
#define N_EDGES 1250000
#define DIM 64

#define B_SHIFT 7
#define BUCKET_NODES 128
#define NBUCKETS ((N_NODES + BUCKET_NODES - 1) / BUCKET_NODES)   // 782
#define CAP 2560            // slots per bucket; mean load 1598, sd ~40
#define PHASES 4
#define BINS (PHASES * BUCKET_NODES)                             // 512
#define P_CHUNK 4096
#define P_THREADS 512
#define EDGES_PER_THREAD (P_CHUNK / P_THREADS)                   // 8
#define NBLK_P ((N_EDGES + P_CHUNK - 1) / P_CHUNK)               // 306
#define N_TILES (N_NODES / 16)                                   // 6250
#define GEMM_BLOCKS ((N_TILES + (P_THREADS / 64) - 1) / (P_THREADS / 64))  // 782
#define SG_THREADS 512

typedef __attribute__((ext_vector_type(8))) short short8;    // 8 bf16 = 4 VGPR
typedef __attribute__((ext_vector_type(4))) float f32x4;

static __host__ __device__ inline size_t align256(size_t x) { return (x + 255) & ~(size_t)255; }

__device__ inline float bf16_to_f32(unsigned short u) {
  return __uint_as_float(((unsigned)u) << 16);
}
__device__ inline float bf16lo_to_f32(unsigned w) {   // low 16 bits = bf16
  return __uint_as_float(w << 16);
}
__device__ inline float bf16hi_to_f32(unsigned w) {   // high 16 bits = bf16
  return __uint_as_float(w & 0xFFFF0000u);
}
__device__ inline unsigned short f32_to_bf16(float f) {
  unsigned u = __float_as_uint(f);
  u += 0x7FFFu + ((u >> 16) & 1u);   // RNE
  return (unsigned short)(u >> 16);
}

// ---------------- Fused: [0, NBLK_P) direct-scatter partition | rest: MFMA GEMM ----------------
// (unchanged; R5 attribution: GEMM ~8us = memory floor, partition ~9-11us across 3 variants)
__global__ __launch_bounds__(P_THREADS) void fused_gemm_partition(
    const float* __restrict__ x,
    const float* __restrict__ W1,
    const float* __restrict__ W2,
    unsigned short* __restrict__ y1b,
    unsigned short* __restrict__ y2b,
    const int* __restrict__ ei,
    int* __restrict__ gcursor,
    unsigned* __restrict__ pairs,
    int nTiles) {
  __shared__ int h[NBUCKETS];
  __shared__ int gb[NBUCKETS];
  __shared__ int cur[NBUCKETS];

  if (blockIdx.x < NBLK_P) {
    const int nE = N_EDGES;
    int tid = threadIdx.x;
    int base = blockIdx.x * P_CHUNK;
    int end = min(base + P_CHUNK, nE);

    for (int i = tid; i < NBUCKETS; i += P_THREADS) h[i] = 0;
    __syncthreads();

    int dstv[EDGES_PER_THREAD], srcv[EDGES_PER_THREAD];
#pragma unroll
    for (int k = 0; k < EDGES_PER_THREAD; ++k) {
      int e = base + tid + k * P_THREADS;
      if (e < end) {
        dstv[k] = ei[nE + e];
        srcv[k] = ei[e];
      } else {
        dstv[k] = -1;
        srcv[k] = 0;
      }
    }
#pragma unroll
    for (int k = 0; k < EDGES_PER_THREAD; ++k)
      if (dstv[k] >= 0) atomicAdd(&h[dstv[k] >> B_SHIFT], 1);
    __syncthreads();

    for (int i = tid; i < NBUCKETS; i += P_THREADS) {
      int c = h[i];
      gb[i] = c ? atomicAdd(&gcursor[i], c) : 0;
      cur[i] = 0;
    }
    __syncthreads();

#pragma unroll
    for (int k = 0; k < EDGES_PER_THREAD; ++k) {
      if (dstv[k] < 0) continue;
      int b = dstv[k] >> B_SHIFT;
      int inb = atomicAdd(&cur[b], 1);
      int gpos = gb[b] + inb;
      if (gpos < CAP)
        pairs[(size_t)b * CAP + gpos] =
            (unsigned)srcv[k] | ((unsigned)(dstv[k] & (BUCKET_NODES - 1)) << 17);
    }
  } else {
    // ---------- GEMM: one wave = ONE 16-row x 64-col tile, both W's ----------
    // Layouts (verified learn_hip m89/m120): A[m][k]: m=lane&15, k=(lane>>4)*8+j;
    // B[k][n]: n=lane&15, same k; C/D: col=lane&15, row=(lane>>4)*4+reg.
    int lane = threadIdx.x & 63;
    int t = ((blockIdx.x - NBLK_P) * P_THREADS + (int)threadIdx.x) >> 6;
    if (t >= nTiles) return;
    int m = lane & 15;
    int q = lane >> 4;

    short8 wf[2][2][4];
#pragma unroll
    for (int w = 0; w < 2; ++w) {
      const float* W = w ? W2 : W1;
#pragma unroll
      for (int kh = 0; kh < 2; ++kh)
#pragma unroll
        for (int nt = 0; nt < 4; ++nt) {
          short8 f;
#pragma unroll
          for (int j = 0; j < 8; ++j) {
            int k = kh * 32 + q * 8 + j;
            f[j] = (short)f32_to_bf16(W[k * DIM + nt * 16 + m]);
          }
          wf[w][kh][nt] = f;
        }
    }

    int rowBase = t * 16;
    const float* xr = x + (size_t)(rowBase + m) * DIM + q * 8;

    short8 af[2];
#pragma unroll
    for (int kh = 0; kh < 2; ++kh) {
      float4 u0 = *(const float4*)(xr + kh * 32);
      float4 u1 = *(const float4*)(xr + kh * 32 + 4);
      short8 f;
      f[0] = (short)f32_to_bf16(u0.x);
      f[1] = (short)f32_to_bf16(u0.y);
      f[2] = (short)f32_to_bf16(u0.z);
      f[3] = (short)f32_to_bf16(u0.w);
      f[4] = (short)f32_to_bf16(u1.x);
      f[5] = (short)f32_to_bf16(u1.y);
      f[6] = (short)f32_to_bf16(u1.z);
      f[7] = (short)f32_to_bf16(u1.w);
      af[kh] = f;
    }

#pragma unroll
    for (int w = 0; w < 2; ++w) {
      unsigned short* Y = w ? y2b : y1b;
      f32x4 acc[4];
#pragma unroll
      for (int nt = 0; nt < 4; ++nt) {
        acc[nt] = (f32x4){0.f, 0.f, 0.f, 0.f};
        acc[nt] = __builtin_amdgcn_mfma_f32_16x16x32_bf16(af[0], wf[w][0][nt], acc[nt], 0, 0, 0);
        acc[nt] = __builtin_amdgcn_mfma_f32_16x16x32_bf16(af[1], wf[w][1][nt], acc[nt], 0, 0, 0);
      }
#pragma unroll
      for (int nt = 0; nt < 4; ++nt)
#pragma unroll
        for (int r = 0; r < 4; ++r)
          Y[(size_t)(rowBase + q * 4 + r) * DIM + nt * 16 + m] = f32_to_bf16(acc[nt][r]);
    }
  }
}

// ---------------- v10: v9 sort + register-pipelined phase-swept gather ----------------
// v9 (-7us, confirmed) left ~15us unexplained slack in the gather: each iteration's FP
// adds WAIT on the loads issued in the same iteration (2 in flight, ~30cy work vs
// ~200+cy L2 latency). v10 software-pipelines in registers: issue next pair's
// index-reads + row-loads BEFORE consuming the current pair, so every wave has a full
// add-block between load issue and s_waitcnt, on top of 8-waves/SIMD TLP.
__global__ __launch_bounds__(SG_THREADS) void sort_gather(
    const unsigned* __restrict__ pairs,
    const int* __restrict__ gcursor,
    const unsigned short* __restrict__ y1b,
    const unsigned short* __restrict__ y2b,
    float* __restrict__ out,
    int nNodesTotal) {
  __shared__ unsigned sorted[CAP];      // 10 KB (src only)
  __shared__ int cnt[BINS];             // 2 KB
  __shared__ int scn[BINS];             // inclusive scan, 2 KB
  __shared__ int cur[BINS];             // placement cursor, 2 KB

  int b = blockIdx.x;
  int n = min(gcursor[b], CAP);
  int tid = threadIdx.x;
  const unsigned* pb = pairs + (size_t)b * CAP;

  for (int i = tid; i < BINS; i += SG_THREADS) cnt[i] = 0;
  __syncthreads();
  for (int i = tid; i < n; i += SG_THREADS) {
    unsigned w = pb[i];
    unsigned src = w & 0x1FFFFu;
    int key = (int)(((src * 5243u) >> 27) << 7) | (int)((w >> 17) & 127u);
    atomicAdd(&cnt[key], 1);
  }
  __syncthreads();

  // wave-0 scan over 512 bins, 8 bins/lane
  if (tid < 64) {
    int k0 = tid * 8;
    int v[8];
    int lsum = 0;
#pragma unroll
    for (int j = 0; j < 8; ++j) { v[j] = cnt[k0 + j]; lsum += v[j]; }
    int s = lsum;
#pragma unroll
    for (int off = 1; off < 64; off <<= 1) {
      int t = __shfl_up(s, off, 64);
      if (tid >= off) s += t;
    }
    int run = s - lsum;
#pragma unroll
    for (int j = 0; j < 8; ++j) {
      cur[k0 + j] = run;
      run += v[j];
      scn[k0 + j] = run;
    }
  }
  __syncthreads();

  for (int i = tid; i < n; i += SG_THREADS) {
    unsigned w = pb[i];                  // L2 re-read instead of LDS buf
    unsigned src = w & 0x1FFFFu;
    int key = (int)(((src * 5243u) >> 27) << 7) | (int)((w >> 17) & 127u);
    int p = atomicAdd(&cur[key], 1);
    sorted[p] = src;
  }
  __syncthreads();

  // ---------- gather: 8-lane group, 2 static nodes/group, register-pipelined ----------
  int gid = tid >> 3;                // 0..63 groups
  int c8 = tid & 7;                  // int4 column (lane owns cols 8*c8 .. 8*c8+7)
  const int4* y2q = (const int4*)y2b;   // row = 8 int4 (128B)
  const int4* y1q = (const int4*)y1b;
  int nodeBase = b << B_SHIFT;
  int numNodes = min(BUCKET_NODES, nNodesTotal - nodeBase);

  float acc[2][8];
#pragma unroll
  for (int nn = 0; nn < 2; ++nn)
#pragma unroll
    for (int j = 0; j < 8; ++j) acc[nn][j] = 0.f;

  for (int p = 0; p < PHASES; ++p) {
#pragma unroll
    for (int nn = 0; nn < 2; ++nn) {
      int ln = gid * 2 + nn;
      int k = (p << 7) | ln;
      int end = scn[k];
      int e = end - cnt[k];
      if (e >= end) continue;

      // prologue: issue first pair of row loads
      int i1 = min(e + 1, end - 1);
      int4 va = y2q[(size_t)sorted[e] * 8 + c8];
      int4 vb = y2q[(size_t)sorted[i1] * 8 + c8];
      bool h2 = (e + 1 < end);
      e += h2 ? 2 : 1;

      while (true) {
        int4 ca = va, cb = vb;     // consume-side copies (register rename)
        bool ch2 = h2;
        bool more = (e < end);
        if (more) {
          // issue NEXT pair before the adds below -> latency overlapped
          int j1 = min(e + 1, end - 1);
          va = y2q[(size_t)sorted[e] * 8 + c8];
          vb = y2q[(size_t)sorted[j1] * 8 + c8];
          h2 = (e + 1 < end);
          e += h2 ? 2 : 1;
        }
#pragma unroll
        for (int j = 0; j < 4; ++j) {
          unsigned w0 = (unsigned)ca[j];
          acc[nn][2 * j]     += bf16lo_to_f32(w0);
          acc[nn][2 * j + 1] += bf16hi_to_f32(w0);
        }
        if (ch2) {
#pragma unroll
          for (int j = 0; j < 4; ++j) {
            unsigned w1 = (unsigned)cb[j];
            acc[nn][2 * j]     += bf16lo_to_f32(w1);
            acc[nn][2 * j + 1] += bf16hi_to_f32(w1);
          }
        }
        if (!more) break;
      }
    }
  }

  // self part + relu + store: lane owns cols [8*c8, 8*c8+8) of its 2 nodes
#pragma unroll
  for (int nn = 0; nn < 2; ++nn) {
    int ln = gid * 2 + nn;
    if (ln < numNodes) {
      int node = nodeBase + ln;
      int4 s1v = y1q[(size_t)node * 8 + c8];
      float4 o0, o1;
      unsigned w0 = (unsigned)s1v[0], w1 = (unsigned)s1v[1];
      unsigned w2 = (unsigned)s1v[2], w3 = (unsigned)s1v[3];
      o0.x = fmaxf(bf16lo_to_f32(w0) + acc[nn][0], 0.0f);
      o0.y = fmaxf(bf16hi_to_f32(w0) + acc[nn][1], 0.0f);
      o0.z = fmaxf(bf16lo_to_f32(w1) + acc[nn][2], 0.0f);
      o0.w = fmaxf(bf16hi_to_f32(w1) + acc[nn][3], 0.0f);
      o1.x = fmaxf(bf16lo_to_f32(w2) + acc[nn][4], 0.0f);
      o1.y = fmaxf(bf16hi_to_f32(w2) + acc[nn][5], 0.0f);
      o1.z = fmaxf(bf16lo_to_f32(w3) + acc[nn][6], 0.0f);
      o1.w = fmaxf(bf16hi_to_f32(w3) + acc[nn][7], 0.0f);
      float4* orow = (float4*)(out + (size_t)node * DIM + c8 * 8);
      orow[0] = o0;
      orow[1] = o1;
    }
  }
}

// ---------------- Fallback path ----------------
__global__ __launch_bounds__(256) void gemm_simple(
    const float* __restrict__ x, const float* __restrict__ W1, const float* __restrict__ W2,
    float* __restrict__ y1, unsigned short* __restrict__ y2b, int n) {
  int row = blockIdx.x * blockDim.x + threadIdx.x;
  if (row >= n) return;
  float xv[DIM];
  const float4* xr = (const float4*)(x + (size_t)row * DIM);
#pragma unroll
  for (int i = 0; i < DIM / 4; ++i) {
    float4 t = xr[i];
    xv[4 * i] = t.x; xv[4 * i + 1] = t.y; xv[4 * i + 2] = t.z; xv[4 * i + 3] = t.w;
  }
#pragma unroll
  for (int m = 0; m < 2; ++m) {
    const float* W = (m == 0) ? W1 : W2;
#pragma unroll
    for (int cc = 0; cc < DIM; cc += 16) {
      float acc[16];
#pragma unroll
      for (int c2 = 0; c2 < 16; ++c2) acc[c2] = 0.0f;
      for (int k = 0; k < DIM; ++k) {
        float xk = xv[k];
        const float* wr = W + k * DIM + cc;
#pragma unroll
        for (int c2 = 0; c2 < 16; ++c2) acc[c2] = fmaf(xk, wr[c2], acc[c2]);
      }
      if (m == 0) {
        for (int c2 = 0; c2 < 16; ++c2) y1[(size_t)row * DIM + cc + c2] = acc[c2];
      } else {
        for (int c2 = 0; c2 < 16; ++c2) y2b[(size_t)row * DIM + cc + c2] = f32_to_bf16(acc[c2]);
      }
    }
  }
}

__global__ __launch_bounds__(256) void scatter_add(const int* __restrict__ ei,
                                                   const unsigned short* __restrict__ y2b,
                                                   float* __restrict__ out, int nE) {
  int gid = blockIdx.x * blockDim.x + threadIdx.x;
  int edge = gid >> 6;
  int lane = threadIdx.x & 63;
  if (edge >= nE) return;
  int src = __builtin_amdgcn_readfirstlane(ei[edge]);
  int dst = __builtin_amdgcn_readfirstlane(ei[nE + edge]);
  atomicAdd(&out[(size_t)dst * DIM + lane], bf16_to_f32(y2b[(size_t)src * DIM + lane]));
}

__global__ __launch_bounds__(256) void relu_inplace(float* __restrict__ out, int n4) {
  int i = blockIdx.x * blockDim.x + threadIdx.x;
  if (i >= n4) return;
  float4* p = (float4*)out;
  float4 v = p[i];
  v.x = fmaxf(v.x, 0.0f);
  v.y = fmaxf(v.y, 0.0f);
  v.z = fmaxf(v.z, 0.0f);
  v.w = fmaxf(v.w, 0.0f);
  p[i] = v;
}

extern "C" void kernel_launch(void* const* d_in, const int* in_sizes, int n_in,
                              void* d_out, int out_size, void* d_ws, size_t ws_size,
                              hipStream_t stream) {
  const float* x  = (const float*)d_in[0];
  const int*   ei = (const int*)d_in[1];
  const float* W1 = (const float*)d_in[2];
  const float* W2 = (const float*)d_in[3];
  float* out = (float*)d_out;

  char* ws = (char*)d_ws;
  size_t off = 0;
  unsigned short* y2b = (unsigned short*)(ws + off); off += align256((size_t)N_NODES * DIM * sizeof(unsigned short));
  unsigned short* y1b = (unsigned short*)(ws + off); off += align256((size_t)N_NODES * DIM * sizeof(unsigned short));
  int* gcursor = (int*)(ws + off);                   off += align256((size_t)NBUCKETS * sizeof(int));
  unsigned* pairs = (unsigned*)(ws + off);           off += align256((size_t)NBUCKETS * CAP * sizeof(unsigned));
  size_t required = off;

  if (ws_size >= required) {
    hipMemsetAsync(gcursor, 0, (size_t)NBUCKETS * sizeof(int), stream);
    fused_gemm_partition<<<NBLK_P + GEMM_BLOCKS, P_THREADS, 0, stream>>>(
        x, W1, W2, y1b, y2b, ei, gcursor, pairs, N_TILES);
    sort_gather<<<NBUCKETS, SG_THREADS, 0, stream>>>(pairs, gcursor, y1b, y2b, out, N_NODES);
  } else {
    {
      int blocks = (N_NODES + 255) / 256;
      gemm_simple<<<blocks, 256, 0, stream>>>(x, W1, W2, out, y2b, N_NODES);
    }
    {
      long long threads = (long long)N_EDGES * 64;
      int blocks = (int)((threads + 255) / 256);
      scatter_add<<<blocks, 256, 0, stream>>>(ei, y2b, out, N_EDGES);
    }
    {
      int n4 = N_NODES * DIM / 4;
      int blocks = (n4 + 255) / 256;
      relu_inplace<<<blocks, 256, 0, stream>>>(out, n4);
    }
  }
}

// Round 11
// 137.049 us; speedup vs baseline: 1.0171x; 1.0171x over previous
//
#include <hip/hip_runtime.h>

#define N_NODES 100000
#define N_EDGES 1250000
#define DIM 64

#define B_SHIFT 7
#define BUCKET_NODES 128
#define NBUCKETS ((N_NODES + BUCKET_NODES - 1) / BUCKET_NODES)   // 782
#define CAP 2560            // slots per bucket; mean load 1598, sd ~40
#define PHASES 4
#define BINS (PHASES * BUCKET_NODES)                             // 512
#define P_CHUNK 4096
#define P_THREADS 512
#define EDGES_PER_THREAD (P_CHUNK / P_THREADS)                   // 8
#define NBLK_P ((N_EDGES + P_CHUNK - 1) / P_CHUNK)               // 306
#define N_TILES (N_NODES / 16)                                   // 6250
#define GEMM_BLOCKS ((N_TILES + (P_THREADS / 64) - 1) / (P_THREADS / 64))  // 782
#define SG_THREADS 512
#define SG_EPT ((CAP + SG_THREADS - 1) / SG_THREADS)             // 5 edges/thread max

typedef __attribute__((ext_vector_type(8))) short short8;    // 8 bf16 = 4 VGPR
typedef __attribute__((ext_vector_type(4))) float f32x4;

static __host__ __device__ inline size_t align256(size_t x) { return (x + 255) & ~(size_t)255; }

__device__ inline float bf16_to_f32(unsigned short u) {
  return __uint_as_float(((unsigned)u) << 16);
}
__device__ inline float bf16lo_to_f32(unsigned w) {   // low 16 bits = bf16
  return __uint_as_float(w << 16);
}
__device__ inline float bf16hi_to_f32(unsigned w) {   // high 16 bits = bf16
  return __uint_as_float(w & 0xFFFF0000u);
}
__device__ inline unsigned short f32_to_bf16(float f) {
  unsigned u = __float_as_uint(f);
  u += 0x7FFFu + ((u >> 16) & 1u);   // RNE
  return (unsigned short)(u >> 16);
}

// ---------------- Fused: [0, NBLK_P) direct-scatter partition | rest: MFMA GEMM ----------------
// (unchanged; R5 attribution: GEMM ~8us = memory floor, partition ~9-11us across 3 variants)
__global__ __launch_bounds__(P_THREADS) void fused_gemm_partition(
    const float* __restrict__ x,
    const float* __restrict__ W1,
    const float* __restrict__ W2,
    unsigned short* __restrict__ y1b,
    unsigned short* __restrict__ y2b,
    const int* __restrict__ ei,
    int* __restrict__ gcursor,
    unsigned* __restrict__ pairs,
    int nTiles) {
  __shared__ int h[NBUCKETS];
  __shared__ int gb[NBUCKETS];
  __shared__ int cur[NBUCKETS];

  if (blockIdx.x < NBLK_P) {
    const int nE = N_EDGES;
    int tid = threadIdx.x;
    int base = blockIdx.x * P_CHUNK;
    int end = min(base + P_CHUNK, nE);

    for (int i = tid; i < NBUCKETS; i += P_THREADS) h[i] = 0;
    __syncthreads();

    int dstv[EDGES_PER_THREAD], srcv[EDGES_PER_THREAD];
#pragma unroll
    for (int k = 0; k < EDGES_PER_THREAD; ++k) {
      int e = base + tid + k * P_THREADS;
      if (e < end) {
        dstv[k] = ei[nE + e];
        srcv[k] = ei[e];
      } else {
        dstv[k] = -1;
        srcv[k] = 0;
      }
    }
#pragma unroll
    for (int k = 0; k < EDGES_PER_THREAD; ++k)
      if (dstv[k] >= 0) atomicAdd(&h[dstv[k] >> B_SHIFT], 1);
    __syncthreads();

    for (int i = tid; i < NBUCKETS; i += P_THREADS) {
      int c = h[i];
      gb[i] = c ? atomicAdd(&gcursor[i], c) : 0;
      cur[i] = 0;
    }
    __syncthreads();

#pragma unroll
    for (int k = 0; k < EDGES_PER_THREAD; ++k) {
      if (dstv[k] < 0) continue;
      int b = dstv[k] >> B_SHIFT;
      int inb = atomicAdd(&cur[b], 1);
      int gpos = gb[b] + inb;
      if (gpos < CAP)
        pairs[(size_t)b * CAP + gpos] =
            (unsigned)srcv[k] | ((unsigned)(dstv[k] & (BUCKET_NODES - 1)) << 17);
    }
  } else {
    // ---------- GEMM: one wave = ONE 16-row x 64-col tile, both W's ----------
    // Layouts (verified learn_hip m89/m120): A[m][k]: m=lane&15, k=(lane>>4)*8+j;
    // B[k][n]: n=lane&15, same k; C/D: col=lane&15, row=(lane>>4)*4+reg.
    int lane = threadIdx.x & 63;
    int t = ((blockIdx.x - NBLK_P) * P_THREADS + (int)threadIdx.x) >> 6;
    if (t >= nTiles) return;
    int m = lane & 15;
    int q = lane >> 4;

    short8 wf[2][2][4];
#pragma unroll
    for (int w = 0; w < 2; ++w) {
      const float* W = w ? W2 : W1;
#pragma unroll
      for (int kh = 0; kh < 2; ++kh)
#pragma unroll
        for (int nt = 0; nt < 4; ++nt) {
          short8 f;
#pragma unroll
          for (int j = 0; j < 8; ++j) {
            int k = kh * 32 + q * 8 + j;
            f[j] = (short)f32_to_bf16(W[k * DIM + nt * 16 + m]);
          }
          wf[w][kh][nt] = f;
        }
    }

    int rowBase = t * 16;
    const float* xr = x + (size_t)(rowBase + m) * DIM + q * 8;

    short8 af[2];
#pragma unroll
    for (int kh = 0; kh < 2; ++kh) {
      float4 u0 = *(const float4*)(xr + kh * 32);
      float4 u1 = *(const float4*)(xr + kh * 32 + 4);
      short8 f;
      f[0] = (short)f32_to_bf16(u0.x);
      f[1] = (short)f32_to_bf16(u0.y);
      f[2] = (short)f32_to_bf16(u0.z);
      f[3] = (short)f32_to_bf16(u0.w);
      f[4] = (short)f32_to_bf16(u1.x);
      f[5] = (short)f32_to_bf16(u1.y);
      f[6] = (short)f32_to_bf16(u1.z);
      f[7] = (short)f32_to_bf16(u1.w);
      af[kh] = f;
    }

#pragma unroll
    for (int w = 0; w < 2; ++w) {
      unsigned short* Y = w ? y2b : y1b;
      f32x4 acc[4];
#pragma unroll
      for (int nt = 0; nt < 4; ++nt) {
        acc[nt] = (f32x4){0.f, 0.f, 0.f, 0.f};
        acc[nt] = __builtin_amdgcn_mfma_f32_16x16x32_bf16(af[0], wf[w][0][nt], acc[nt], 0, 0, 0);
        acc[nt] = __builtin_amdgcn_mfma_f32_16x16x32_bf16(af[1], wf[w][1][nt], acc[nt], 0, 0, 0);
      }
#pragma unroll
      for (int nt = 0; nt < 4; ++nt)
#pragma unroll
        for (int r = 0; r < 4; ++r)
          Y[(size_t)(rowBase + q * 4 + r) * DIM + nt * 16 + m] = f32_to_bf16(acc[nt][r]);
    }
  }
}

// ---------------- v11: v9 gather (best: 136.6us) + register-cached sort passes ----------------
// R10's register pipeline regressed (-2.8us) -> reverted. v11 = v9 verbatim except the
// sort passes cache (key, src) in registers across histogram->placement (same pattern
// as the partition kernel's dstv/srcv), saving one pairs re-read + key recompute.
// Gather ledger: serial 34.8 | 4-wide ILP ~0 | balanced queue ~0 | L2 phase-sweep -7 |
// reg pipeline -2.8 (regress). v9's phase-swept form ~= the cache-hierarchy floor.
__global__ __launch_bounds__(SG_THREADS) void sort_gather(
    const unsigned* __restrict__ pairs,
    const int* __restrict__ gcursor,
    const unsigned short* __restrict__ y1b,
    const unsigned short* __restrict__ y2b,
    float* __restrict__ out,
    int nNodesTotal) {
  __shared__ unsigned sorted[CAP];      // 10 KB (src only)
  __shared__ int cnt[BINS];             // 2 KB
  __shared__ int scn[BINS];             // inclusive scan, 2 KB
  __shared__ int cur[BINS];             // placement cursor, 2 KB

  int b = blockIdx.x;
  int n = min(gcursor[b], CAP);
  int tid = threadIdx.x;
  const unsigned* pb = pairs + (size_t)b * CAP;

  for (int i = tid; i < BINS; i += SG_THREADS) cnt[i] = 0;
  __syncthreads();

  // single read of pairs; (key, src) cached in registers across both passes
  int ekey[SG_EPT];
  unsigned esrc[SG_EPT];
#pragma unroll
  for (int k = 0; k < SG_EPT; ++k) {
    int i = tid + k * SG_THREADS;
    if (i < n) {
      unsigned w = pb[i];
      unsigned src = w & 0x1FFFFu;
      ekey[k] = (int)(((src * 5243u) >> 27) << 7) | (int)((w >> 17) & 127u);
      esrc[k] = src;
      atomicAdd(&cnt[ekey[k]], 1);
    } else {
      ekey[k] = -1;
    }
  }
  __syncthreads();

  // wave-0 scan over 512 bins, 8 bins/lane
  if (tid < 64) {
    int k0 = tid * 8;
    int v[8];
    int lsum = 0;
#pragma unroll
    for (int j = 0; j < 8; ++j) { v[j] = cnt[k0 + j]; lsum += v[j]; }
    int s = lsum;
#pragma unroll
    for (int off = 1; off < 64; off <<= 1) {
      int t = __shfl_up(s, off, 64);
      if (tid >= off) s += t;
    }
    int run = s - lsum;
#pragma unroll
    for (int j = 0; j < 8; ++j) {
      cur[k0 + j] = run;
      run += v[j];
      scn[k0 + j] = run;
    }
  }
  __syncthreads();

#pragma unroll
  for (int k = 0; k < SG_EPT; ++k) {
    if (ekey[k] >= 0) {
      int p = atomicAdd(&cur[ekey[k]], 1);
      sorted[p] = esrc[k];
    }
  }
  __syncthreads();

  // ---------- gather: 8-lane group, 2 static nodes/group, phase-major sweep ----------
  int gid = tid >> 3;                // 0..63 groups
  int c8 = tid & 7;                  // int4 column (lane owns cols 8*c8 .. 8*c8+7)
  const int4* y2q = (const int4*)y2b;   // row = 8 int4 (128B)
  const int4* y1q = (const int4*)y1b;
  int nodeBase = b << B_SHIFT;
  int numNodes = min(BUCKET_NODES, nNodesTotal - nodeBase);

  float acc[2][8];
#pragma unroll
  for (int nn = 0; nn < 2; ++nn)
#pragma unroll
    for (int j = 0; j < 8; ++j) acc[nn][j] = 0.f;

  for (int p = 0; p < PHASES; ++p) {
#pragma unroll
    for (int nn = 0; nn < 2; ++nn) {
      int ln = gid * 2 + nn;
      int k = (p << 7) | ln;
      int end = scn[k];
      int e = end - cnt[k];
      for (; e + 1 < end; e += 2) {
        int s0 = (int)sorted[e];
        int s1 = (int)sorted[e + 1];
        int4 v0 = y2q[(size_t)s0 * 8 + c8];
        int4 v1 = y2q[(size_t)s1 * 8 + c8];
#pragma unroll
        for (int j = 0; j < 4; ++j) {
          unsigned w0 = (unsigned)v0[j];
          unsigned w1 = (unsigned)v1[j];
          acc[nn][2 * j]     += bf16lo_to_f32(w0) + bf16lo_to_f32(w1);
          acc[nn][2 * j + 1] += bf16hi_to_f32(w0) + bf16hi_to_f32(w1);
        }
      }
      if (e < end) {
        int s0 = (int)sorted[e];
        int4 v0 = y2q[(size_t)s0 * 8 + c8];
#pragma unroll
        for (int j = 0; j < 4; ++j) {
          unsigned w0 = (unsigned)v0[j];
          acc[nn][2 * j]     += bf16lo_to_f32(w0);
          acc[nn][2 * j + 1] += bf16hi_to_f32(w0);
        }
      }
    }
  }

  // self part + relu + store: lane owns cols [8*c8, 8*c8+8) of its 2 nodes
#pragma unroll
  for (int nn = 0; nn < 2; ++nn) {
    int ln = gid * 2 + nn;
    if (ln < numNodes) {
      int node = nodeBase + ln;
      int4 s1v = y1q[(size_t)node * 8 + c8];
      float4 o0, o1;
      unsigned w0 = (unsigned)s1v[0], w1 = (unsigned)s1v[1];
      unsigned w2 = (unsigned)s1v[2], w3 = (unsigned)s1v[3];
      o0.x = fmaxf(bf16lo_to_f32(w0) + acc[nn][0], 0.0f);
      o0.y = fmaxf(bf16hi_to_f32(w0) + acc[nn][1], 0.0f);
      o0.z = fmaxf(bf16lo_to_f32(w1) + acc[nn][2], 0.0f);
      o0.w = fmaxf(bf16hi_to_f32(w1) + acc[nn][3], 0.0f);
      o1.x = fmaxf(bf16lo_to_f32(w2) + acc[nn][4], 0.0f);
      o1.y = fmaxf(bf16hi_to_f32(w2) + acc[nn][5], 0.0f);
      o1.z = fmaxf(bf16lo_to_f32(w3) + acc[nn][6], 0.0f);
      o1.w = fmaxf(bf16hi_to_f32(w3) + acc[nn][7], 0.0f);
      float4* orow = (float4*)(out + (size_t)node * DIM + c8 * 8);
      orow[0] = o0;
      orow[1] = o1;
    }
  }
}

// ---------------- Fallback path ----------------
__global__ __launch_bounds__(256) void gemm_simple(
    const float* __restrict__ x, const float* __restrict__ W1, const float* __restrict__ W2,
    float* __restrict__ y1, unsigned short* __restrict__ y2b, int n) {
  int row = blockIdx.x * blockDim.x + threadIdx.x;
  if (row >= n) return;
  float xv[DIM];
  const float4* xr = (const float4*)(x + (size_t)row * DIM);
#pragma unroll
  for (int i = 0; i < DIM / 4; ++i) {
    float4 t = xr[i];
    xv[4 * i] = t.x; xv[4 * i + 1] = t.y; xv[4 * i + 2] = t.z; xv[4 * i + 3] = t.w;
  }
#pragma unroll
  for (int m = 0; m < 2; ++m) {
    const float* W = (m == 0) ? W1 : W2;
#pragma unroll
    for (int cc = 0; cc < DIM; cc += 16) {
      float acc[16];
#pragma unroll
      for (int c2 = 0; c2 < 16; ++c2) acc[c2] = 0.0f;
      for (int k = 0; k < DIM; ++k) {
        float xk = xv[k];
        const float* wr = W + k * DIM + cc;
#pragma unroll
        for (int c2 = 0; c2 < 16; ++c2) acc[c2] = fmaf(xk, wr[c2], acc[c2]);
      }
      if (m == 0) {
        for (int c2 = 0; c2 < 16; ++c2) y1[(size_t)row * DIM + cc + c2] = acc[c2];
      } else {
        for (int c2 = 0; c2 < 16; ++c2) y2b[(size_t)row * DIM + cc + c2] = f32_to_bf16(acc[c2]);
      }
    }
  }
}

__global__ __launch_bounds__(256) void scatter_add(const int* __restrict__ ei,
                                                   const unsigned short* __restrict__ y2b,
                                                   float* __restrict__ out, int nE) {
  int gid = blockIdx.x * blockDim.x + threadIdx.x;
  int edge = gid >> 6;
  int lane = threadIdx.x & 63;
  if (edge >= nE) return;
  int src = __builtin_amdgcn_readfirstlane(ei[edge]);
  int dst = __builtin_amdgcn_readfirstlane(ei[nE + edge]);
  atomicAdd(&out[(size_t)dst * DIM + lane], bf16_to_f32(y2b[(size_t)src * DIM + lane]));
}

__global__ __launch_bounds__(256) void relu_inplace(float* __restrict__ out, int n4) {
  int i = blockIdx.x * blockDim.x + threadIdx.x;
  if (i >= n4) return;
  float4* p = (float4*)out;
  float4 v = p[i];
  v.x = fmaxf(v.x, 0.0f);
  v.y = fmaxf(v.y, 0.0f);
  v.z = fmaxf(v.z, 0.0f);
  v.w = fmaxf(v.w, 0.0f);
  p[i] = v;
}

extern "C" void kernel_launch(void* const* d_in, const int* in_sizes, int n_in,
                              void* d_out, int out_size, void* d_ws, size_t ws_size,
                              hipStream_t stream) {
  const float* x  = (const float*)d_in[0];
  const int*   ei = (const int*)d_in[1];
  const float* W1 = (const float*)d_in[2];
  const float* W2 = (const float*)d_in[3];
  float* out = (float*)d_out;

  char* ws = (char*)d_ws;
  size_t off = 0;
  unsigned short* y2b = (unsigned short*)(ws + off); off += align256((size_t)N_NODES * DIM * sizeof(unsigned short));
  unsigned short* y1b = (unsigned short*)(ws + off); off += align256((size_t)N_NODES * DIM * sizeof(unsigned short));
  int* gcursor = (int*)(ws + off);                   off += align256((size_t)NBUCKETS * sizeof(int));
  unsigned* pairs = (unsigned*)(ws + off);           off += align256((size_t)NBUCKETS * CAP * sizeof(unsigned));
  size_t required = off;

  if (ws_size >= required) {
    hipMemsetAsync(gcursor, 0, (size_t)NBUCKETS * sizeof(int), stream);
    fused_gemm_partition<<<NBLK_P + GEMM_BLOCKS, P_THREADS, 0, stream>>>(
        x, W1, W2, y1b, y2b, ei, gcursor, pairs, N_TILES);
    sort_gather<<<NBUCKETS, SG_THREADS, 0, stream>>>(pairs, gcursor, y1b, y2b, out, N_NODES);
  } else {
    {
      int blocks = (N_NODES + 255) / 256;
      gemm_simple<<<blocks, 256, 0, stream>>>(x, W1, W2, out, y2b, N_NODES);
    }
    {
      long long threads = (long long)N_EDGES * 64;
      int blocks = (int)((threads + 255) / 256);
      scatter_add<<<blocks, 256, 0, stream>>>(ei, y2b, out, N_EDGES);
    }
    {
      int n4 = N_NODES * DIM / 4;
      int blocks = (n4 + 255) / 256;
      relu_inplace<<<blocks, 256, 0, stream>>>(out, n4);
    }
  }
}